// Round 6
// baseline (213.487 us; speedup 1.0000x reference)
//
#include <hip/hip_runtime.h>

#define B_ 8
#define C_ 256
#define N_ 4096
#define NSPLIT 8

typedef float f32x4 __attribute__((ext_vector_type(4)));
typedef __bf16 bf16x8 __attribute__((ext_vector_type(8)));
typedef unsigned short u16x8 __attribute__((ext_vector_type(8)));
typedef unsigned short u16x4 __attribute__((ext_vector_type(4)));

__device__ __forceinline__ unsigned short f2bf(float f) {
  unsigned u = __float_as_uint(f);
  u += 0x7fff + ((u >> 16) & 1);   // RNE; inputs finite
  return (unsigned short)(u >> 16);
}

__device__ __forceinline__ f32x4 mfma16(bf16x8 a, bf16x8 b, f32x4 c) {
  return __builtin_amdgcn_mfma_f32_16x16x32_bf16(a, b, c, 0, 0, 0);
}

typedef __attribute__((address_space(1))) const void* gvp;
typedef __attribute__((address_space(3))) void* lvp;
__device__ __forceinline__ void gld16(const void* g, void* l) {
  __builtin_amdgcn_global_load_lds((gvp)g, (lvp)l, 16, 0, 0);
}

// Swizzled LDS tile: ROWS x 64 bf16, pitch 64 u16 (128 B); chunk c of row r at
// slot c^(r&7). Staged wave-cooperatively with global_load_lds (16 B/lane).
template <int ROWS>
__device__ __forceinline__ void stage(unsigned short* lds, const unsigned short* g,
                                      int ld, int w, int lane) {
  const int r8 = lane >> 3;
  const int ce = ((lane & 7) ^ r8) << 3;
  const unsigned short* gp = g + (size_t)(w * (ROWS / 4) + r8) * ld + ce;
  unsigned short* lp = lds + w * (ROWS / 4) * 64;
#pragma unroll
  for (int i = 0; i < ROWS / 32; i++)
    gld16(gp + (size_t)(i * 8) * ld, lp + i * 512);
}

__device__ __forceinline__ bf16x8 frag(const unsigned short* lds, int row, int kc) {
  return *(const bf16x8*)(lds + row * 64 + ((kc ^ (row & 7)) << 3));
}

// ---------------------------------------------------------------------------
// P1: cast weights fp32 -> bf16
__global__ __launch_bounds__(256) void castw(
    const float* __restrict__ wq, const float* __restrict__ wkv,
    const float* __restrict__ wo, unsigned short* __restrict__ wqb,
    unsigned short* __restrict__ wkvb, unsigned short* __restrict__ wob) {
  int i = (blockIdx.x * 256 + threadIdx.x) * 4;
  const float* src;
  unsigned short* dst;
  int off;
  if (i < 65536) { src = wq; dst = wqb; off = i; }
  else if (i < 196608) { src = wkv; dst = wkvb; off = i - 65536; }
  else { src = wo; dst = wob; off = i - 196608; }
  float4 v = *(const float4*)(src + off);
  *(u16x4*)(dst + off) = (u16x4){f2bf(v.x), f2bf(v.y), f2bf(v.z), f2bf(v.w)};
}

// ---------------------------------------------------------------------------
// P2: xT[b][n][c] bf16 = transpose(x[b][c][n]); ditto cproj -> cpT.
// 4x4 register-block transpose: coalesced float4 reads, ds_write_b64, b128 out.
__global__ __launch_bounds__(256) void transpose_cast(
    const float* __restrict__ x, const float* __restrict__ cp,
    unsigned short* __restrict__ xT, unsigned short* __restrict__ cpT) {
  __shared__ unsigned short tr[64][72];
  const int z = blockIdx.z, b = z >> 1;
  const float* src = (z & 1) ? cp : x;
  unsigned short* dst = (z & 1) ? cpT : xT;
  const int c0 = blockIdx.y * 64, n0 = blockIdx.x * 64;
  const int t = threadIdx.x;
  const int r0 = (t >> 4) * 4;     // channel-row group
  const int nq = (t & 15) * 4;     // n-col group (lanes 0-15 cover 256 B of a row)
  const float* sp = src + ((size_t)b * C_ + c0 + r0) * N_ + n0 + nq;
  float4 v[4];
#pragma unroll
  for (int i = 0; i < 4; i++) v[i] = *(const float4*)(sp + (size_t)i * N_);
#pragma unroll
  for (int j = 0; j < 4; j++) {
    u16x4 o = (u16x4){f2bf(((const float*)&v[0])[j]), f2bf(((const float*)&v[1])[j]),
                      f2bf(((const float*)&v[2])[j]), f2bf(((const float*)&v[3])[j])};
    *(u16x4*)&tr[nq + j][r0] = o;
  }
  __syncthreads();
  const int nr = t >> 2, cg = (t & 3) * 16;
  unsigned short* dp = dst + ((size_t)b * N_ + n0 + nr) * C_ + c0 + cg;
  *(u16x8*)dp = *(const u16x8*)&tr[nr][cg];
  *(u16x8*)(dp + 8) = *(const u16x8*)&tr[nr][cg + 8];
}

// ---------------------------------------------------------------------------
// G1: qT[b][n][m] = softmax_d((wq @ x + bq) * 0.25). NT GEMM, M-tile 256 (full
// C, xT read ONCE) x N-tile 64, BK=64. Wave w owns head w (64 rows) x 64 cols.
__global__ __launch_bounds__(256) void qproj(
    const unsigned short* __restrict__ wqb, const unsigned short* __restrict__ xT,
    const float* __restrict__ bq, unsigned short* __restrict__ qT) {
  __shared__ __align__(16) unsigned short As[256 * 64];
  __shared__ __align__(16) unsigned short Bs[64 * 64];
  const int b = blockIdx.z, n0 = blockIdx.x * 64;
  const int tid = threadIdx.x, lane = tid & 63, w = tid >> 6;
  const int m0w = w * 64;
  const int colL = lane & 15, kq = lane >> 4, quad = lane >> 4;
  const unsigned short* Bg = xT + ((size_t)b * N_ + n0) * C_;

  f32x4 acc[4][4];
#pragma unroll
  for (int i = 0; i < 4; i++)
#pragma unroll
    for (int j = 0; j < 4; j++) acc[i][j] = (f32x4){0.f, 0.f, 0.f, 0.f};

  for (int kt = 0; kt < 4; kt++) {
    stage<256>(As, wqb + kt * 64, C_, w, lane);
    stage<64>(Bs, Bg + kt * 64, C_, w, lane);
    __syncthreads();
#pragma unroll
    for (int ks = 0; ks < 2; ks++) {
      bf16x8 af[4], bf[4];
#pragma unroll
      for (int mt = 0; mt < 4; mt++) af[mt] = frag(As, m0w + mt * 16 + colL, ks * 4 + kq);
#pragma unroll
      for (int nt = 0; nt < 4; nt++) bf[nt] = frag(Bs, nt * 16 + colL, ks * 4 + kq);
#pragma unroll
      for (int mt = 0; mt < 4; mt++)
#pragma unroll
        for (int nt = 0; nt < 4; nt++) acc[mt][nt] = mfma16(af[mt], bf[nt], acc[mt][nt]);
    }
    __syncthreads();
  }

  // per-column softmax over this wave's head (64 channels)
#pragma unroll
  for (int nt = 0; nt < 4; nt++) {
    float v[16];
    float mx = -1e30f;
#pragma unroll
    for (int mt = 0; mt < 4; mt++)
#pragma unroll
      for (int r = 0; r < 4; r++) {
        int m = m0w + mt * 16 + quad * 4 + r;
        float val = (acc[mt][nt][r] + bq[m]) * 0.25f;
        v[mt * 4 + r] = val;
        mx = fmaxf(mx, val);
      }
    mx = fmaxf(mx, __shfl_xor(mx, 16));
    mx = fmaxf(mx, __shfl_xor(mx, 32));
    float s = 0.f;
#pragma unroll
    for (int j = 0; j < 16; j++) { v[j] = __expf(v[j] - mx); s += v[j]; }
    s += __shfl_xor(s, 16);
    s += __shfl_xor(s, 32);
    float inv = 1.0f / s;
    const int n = n0 + nt * 16 + colL;
    unsigned short* qb = qT + ((size_t)b * N_ + n) * C_ + m0w;
#pragma unroll
    for (int mt = 0; mt < 4; mt++) {
      u16x4 o = (u16x4){f2bf(v[mt * 4 + 0] * inv), f2bf(v[mt * 4 + 1] * inv),
                        f2bf(v[mt * 4 + 2] * inv), f2bf(v[mt * 4 + 3] * inv)};
      *(u16x4*)(qb + mt * 16 + quad * 4) = o;
    }
  }
}

// ---------------------------------------------------------------------------
// G2: KV = wkv @ cproj + bkv. NT GEMM, M-tile 512 (full KVC, cpT read ONCE)
// x N-tile 64, BK=64. Wave w owns rows w*128..+128. K rows -> fp32, V -> bf16.
__global__ __launch_bounds__(256) void kvproj(
    const unsigned short* __restrict__ wkvb, const unsigned short* __restrict__ cpT,
    const float* __restrict__ bkv, float* __restrict__ Kf,
    unsigned short* __restrict__ Vb) {
  __shared__ __align__(16) unsigned short As[512 * 64];
  __shared__ __align__(16) unsigned short Bs[64 * 64];
  const int b = blockIdx.z, n0 = blockIdx.x * 64;
  const int tid = threadIdx.x, lane = tid & 63, w = tid >> 6;
  const int m0w = w * 128;
  const int colL = lane & 15, kq = lane >> 4, quad = lane >> 4;
  const unsigned short* Bg = cpT + ((size_t)b * N_ + n0) * C_;

  f32x4 acc[8][4];
#pragma unroll
  for (int i = 0; i < 8; i++)
#pragma unroll
    for (int j = 0; j < 4; j++) acc[i][j] = (f32x4){0.f, 0.f, 0.f, 0.f};

  for (int kt = 0; kt < 4; kt++) {
    stage<512>(As, wkvb + kt * 64, C_, w, lane);
    stage<64>(Bs, Bg + kt * 64, C_, w, lane);
    __syncthreads();
#pragma unroll
    for (int ks = 0; ks < 2; ks++) {
      bf16x8 bf[4];
#pragma unroll
      for (int nt = 0; nt < 4; nt++) bf[nt] = frag(Bs, nt * 16 + colL, ks * 4 + kq);
#pragma unroll
      for (int mt = 0; mt < 8; mt++) {
        bf16x8 af = frag(As, m0w + mt * 16 + colL, ks * 4 + kq);
#pragma unroll
        for (int nt = 0; nt < 4; nt++) acc[mt][nt] = mfma16(af, bf[nt], acc[mt][nt]);
      }
    }
    __syncthreads();
  }

#pragma unroll
  for (int mt = 0; mt < 8; mt++)
#pragma unroll
    for (int r = 0; r < 4; r++) {
      int m = m0w + mt * 16 + quad * 4 + r;
      float bias = bkv[m];
      if (m < C_) {
        float* kr = Kf + ((size_t)b * C_ + m) * N_ + n0;
#pragma unroll
        for (int nt = 0; nt < 4; nt++) kr[nt * 16 + colL] = acc[mt][nt][r] + bias;
      } else {
        unsigned short* vr = Vb + ((size_t)b * C_ + m - C_) * N_ + n0;
#pragma unroll
        for (int nt = 0; nt < 4; nt++) vr[nt * 16 + colL] = f2bf(acc[mt][nt][r] + bias);
      }
    }
}

// ---------------------------------------------------------------------------
// G3: kb = softmax_N(Kf) bf16, one block per (b, c) row of 4096.
__global__ __launch_bounds__(256) void ksoftmax(const float* __restrict__ Kf,
                                                unsigned short* __restrict__ kb) {
  const int b = blockIdx.x >> 8, c = blockIdx.x & 255;
  const float* row = Kf + ((size_t)b * C_ + c) * N_;
  unsigned short* orow = kb + ((size_t)b * C_ + c) * N_;
  const int t = threadIdx.x, lane = t & 63, wv = t >> 6;
  __shared__ float red[8];

  float4 v[4];
  float mx = -1e30f;
#pragma unroll
  for (int i = 0; i < 4; i++) {
    v[i] = *(const float4*)&row[i * 1024 + t * 4];
    mx = fmaxf(fmaxf(fmaxf(mx, v[i].x), fmaxf(v[i].y, v[i].z)), v[i].w);
  }
#pragma unroll
  for (int o = 32; o > 0; o >>= 1) mx = fmaxf(mx, __shfl_down(mx, o));
  if (lane == 0) red[wv] = mx;
  __syncthreads();
  mx = fmaxf(fmaxf(red[0], red[1]), fmaxf(red[2], red[3]));

  float s = 0.f;
#pragma unroll
  for (int i = 0; i < 4; i++) {
    v[i].x = __expf(v[i].x - mx); v[i].y = __expf(v[i].y - mx);
    v[i].z = __expf(v[i].z - mx); v[i].w = __expf(v[i].w - mx);
    s += v[i].x + v[i].y + v[i].z + v[i].w;
  }
#pragma unroll
  for (int o = 32; o > 0; o >>= 1) s += __shfl_down(s, o);
  if (lane == 0) red[4 + wv] = s;
  __syncthreads();
  float inv = 1.0f / (red[4] + red[5] + red[6] + red[7]);
#pragma unroll
  for (int i = 0; i < 4; i++) {
    u16x4 o = (u16x4){f2bf(v[i].x * inv), f2bf(v[i].y * inv),
                      f2bf(v[i].z * inv), f2bf(v[i].w * inv)};
    *(u16x4*)&orow[i * 1024 + t * 4] = o;
  }
}

// ---------------------------------------------------------------------------
// G4: ctxp[s][b][c][d] = sum_{n in split s} kb[b][c][n] * Vb[b][d][n].
// NT GEMM 128x64, BK=64.
__global__ __launch_bounds__(256) void ctx_part(
    const unsigned short* __restrict__ kb, const unsigned short* __restrict__ Vb,
    float* __restrict__ ctxp) {
  __shared__ __align__(16) unsigned short As[128 * 64];
  __shared__ __align__(16) unsigned short Bs[64 * 64];
  const int z = blockIdx.z, b = z >> 3, s = z & 7;
  const int m0 = blockIdx.y * 128, n0 = blockIdx.x * 64;
  const int tid = threadIdx.x, lane = tid & 63, w = tid >> 6;
  const int m0w = (w & 1) * 64, n0w = (w >> 1) * 32;
  const int colL = lane & 15, kq = lane >> 4, quad = lane >> 4;
  const unsigned short* Ag = kb + ((size_t)b * C_ + m0) * N_;
  const unsigned short* Bg = Vb + ((size_t)b * C_ + n0) * N_;
  const int kbeg = s * (N_ / NSPLIT);

  f32x4 acc[4][2];
#pragma unroll
  for (int i = 0; i < 4; i++)
#pragma unroll
    for (int j = 0; j < 2; j++) acc[i][j] = (f32x4){0.f, 0.f, 0.f, 0.f};

  for (int kt = 0; kt < (N_ / NSPLIT) / 64; kt++) {
    stage<128>(As, Ag + kbeg + kt * 64, N_, w, lane);
    stage<64>(Bs, Bg + kbeg + kt * 64, N_, w, lane);
    __syncthreads();
#pragma unroll
    for (int ks = 0; ks < 2; ks++) {
      bf16x8 af[4], bf[2];
#pragma unroll
      for (int mt = 0; mt < 4; mt++) af[mt] = frag(As, m0w + mt * 16 + colL, ks * 4 + kq);
#pragma unroll
      for (int nt = 0; nt < 2; nt++) bf[nt] = frag(Bs, n0w + nt * 16 + colL, ks * 4 + kq);
#pragma unroll
      for (int mt = 0; mt < 4; mt++)
#pragma unroll
        for (int nt = 0; nt < 2; nt++) acc[mt][nt] = mfma16(af[mt], bf[nt], acc[mt][nt]);
    }
    __syncthreads();
  }

  float* outp = ctxp + ((size_t)s * B_ + b) * C_ * C_;
#pragma unroll
  for (int mt = 0; mt < 4; mt++)
#pragma unroll
    for (int nt = 0; nt < 2; nt++)
#pragma unroll
      for (int r = 0; r < 4; r++) {
        int m = m0 + m0w + mt * 16 + quad * 4 + r;
        int n = n0 + n0w + nt * 16 + colL;
        outp[(size_t)m * C_ + n] = acc[mt][nt][r];
      }
}

// ---------------------------------------------------------------------------
// R: ctxsT[b][d][c] bf16 = transpose(sum over 8 split partials).
__global__ __launch_bounds__(256) void ctx_reduce_t(const float* __restrict__ ctxp,
                                                    unsigned short* __restrict__ ctxsT) {
  __shared__ unsigned short t[64][72];
  const int b = blockIdx.z, c0 = blockIdx.y * 64, d0 = blockIdx.x * 64;
  const int tid = threadIdx.x;
  const int cl = tid >> 2, dg = (tid & 3) * 16;
  const float* base = ctxp + ((size_t)b * C_ + c0 + cl) * C_ + d0 + dg;
  float acc[16];
#pragma unroll
  for (int j = 0; j < 16; j++) acc[j] = 0.f;
  for (int s = 0; s < NSPLIT; s++) {
    const float* p = base + (size_t)s * B_ * C_ * C_;
#pragma unroll
    for (int j = 0; j < 16; j += 4) {
      float4 v = *(const float4*)(p + j);
      acc[j] += v.x; acc[j + 1] += v.y; acc[j + 2] += v.z; acc[j + 3] += v.w;
    }
  }
#pragma unroll
  for (int j = 0; j < 16; j++) t[dg + j][cl] = f2bf(acc[j]);
  __syncthreads();
  const int dr = tid >> 2, cg = (tid & 3) * 16;
  unsigned short* dp = ctxsT + ((size_t)b * C_ + d0 + dr) * C_ + c0 + cg;
  *(u16x8*)dp = *(const u16x8*)&t[dr][cg];
  *(u16x8*)(dp + 8) = *(const u16x8*)&t[dr][cg + 8];
}

// ---------------------------------------------------------------------------
// G5: ctx2[b][o][d] = wo @ ctx. NT GEMM 128x128, BK=64.
__global__ __launch_bounds__(256) void oproj(
    const unsigned short* __restrict__ wob, const unsigned short* __restrict__ ctxsT,
    unsigned short* __restrict__ ctx2) {
  __shared__ __align__(16) unsigned short As[128 * 64];
  __shared__ __align__(16) unsigned short Bs[128 * 64];
  const int b = blockIdx.z, m0 = blockIdx.y * 128, n0 = blockIdx.x * 128;
  const int tid = threadIdx.x, lane = tid & 63, w = tid >> 6;
  const int m0w = (w >> 1) * 64, n0w = (w & 1) * 64;
  const int colL = lane & 15, kq = lane >> 4, quad = lane >> 4;
  const unsigned short* Ag = wob + (size_t)m0 * C_;
  const unsigned short* Bg = ctxsT + ((size_t)b * C_ + n0) * C_;

  f32x4 acc[4][4];
#pragma unroll
  for (int i = 0; i < 4; i++)
#pragma unroll
    for (int j = 0; j < 4; j++) acc[i][j] = (f32x4){0.f, 0.f, 0.f, 0.f};

  for (int kt = 0; kt < 4; kt++) {
    stage<128>(As, Ag + kt * 64, C_, w, lane);
    stage<128>(Bs, Bg + kt * 64, C_, w, lane);
    __syncthreads();
#pragma unroll
    for (int ks = 0; ks < 2; ks++) {
      bf16x8 af[4], bf[4];
#pragma unroll
      for (int mt = 0; mt < 4; mt++) af[mt] = frag(As, m0w + mt * 16 + colL, ks * 4 + kq);
#pragma unroll
      for (int nt = 0; nt < 4; nt++) bf[nt] = frag(Bs, n0w + nt * 16 + colL, ks * 4 + kq);
#pragma unroll
      for (int mt = 0; mt < 4; mt++)
#pragma unroll
        for (int nt = 0; nt < 4; nt++) acc[mt][nt] = mfma16(af[mt], bf[nt], acc[mt][nt]);
    }
    __syncthreads();
  }

  unsigned short* ob = ctx2 + (size_t)b * C_ * C_;
#pragma unroll
  for (int mt = 0; mt < 4; mt++)
#pragma unroll
    for (int nt = 0; nt < 4; nt++)
#pragma unroll
      for (int r = 0; r < 4; r++) {
        int m = m0 + m0w + mt * 16 + quad * 4 + r;
        int n = n0 + n0w + nt * 16 + colL;
        ob[(size_t)m * C_ + n] = f2bf(acc[mt][nt][r]);
      }
}

// ---------------------------------------------------------------------------
// G6: out[b][m][n] = sum_d ctx2[b][m][d] * qT[b][n][d] + bo[m]. NT GEMM,
// M-tile 256 (full ctx2, qT read ONCE) x N-tile 64, BK=64.
__global__ __launch_bounds__(256) void outgemm(
    const unsigned short* __restrict__ ctx2, const unsigned short* __restrict__ qT,
    const float* __restrict__ bo, float* __restrict__ out) {
  __shared__ __align__(16) unsigned short As[256 * 64];
  __shared__ __align__(16) unsigned short Bs[64 * 64];
  const int b = blockIdx.z, n0 = blockIdx.x * 64;
  const int tid = threadIdx.x, lane = tid & 63, w = tid >> 6;
  const int m0w = w * 64;
  const int colL = lane & 15, kq = lane >> 4, quad = lane >> 4;
  const unsigned short* Ag = ctx2 + (size_t)b * C_ * C_;
  const unsigned short* Bg = qT + ((size_t)b * N_ + n0) * C_;

  f32x4 acc[4][4];
#pragma unroll
  for (int i = 0; i < 4; i++)
#pragma unroll
    for (int j = 0; j < 4; j++) acc[i][j] = (f32x4){0.f, 0.f, 0.f, 0.f};

  for (int kt = 0; kt < 4; kt++) {
    stage<256>(As, Ag + kt * 64, C_, w, lane);
    stage<64>(Bs, Bg + kt * 64, C_, w, lane);
    __syncthreads();
#pragma unroll
    for (int ks = 0; ks < 2; ks++) {
      bf16x8 af[4], bf[4];
#pragma unroll
      for (int mt = 0; mt < 4; mt++) af[mt] = frag(As, m0w + mt * 16 + colL, ks * 4 + kq);
#pragma unroll
      for (int nt = 0; nt < 4; nt++) bf[nt] = frag(Bs, nt * 16 + colL, ks * 4 + kq);
#pragma unroll
      for (int mt = 0; mt < 4; mt++)
#pragma unroll
        for (int nt = 0; nt < 4; nt++) acc[mt][nt] = mfma16(af[mt], bf[nt], acc[mt][nt]);
    }
    __syncthreads();
  }

  float* ob = out + (size_t)b * C_ * N_;
#pragma unroll
  for (int mt = 0; mt < 4; mt++)
#pragma unroll
    for (int r = 0; r < 4; r++) {
      int m = m0w + mt * 16 + quad * 4 + r;
      float bias = bo[m];
#pragma unroll
      for (int nt = 0; nt < 4; nt++) {
        int n = n0 + nt * 16 + colL;
        ob[(size_t)m * N_ + n] = acc[mt][nt][r] + bias;
      }
    }
}

// ---------------------------------------------------------------------------
extern "C" void kernel_launch(void* const* d_in, const int* in_sizes, int n_in,
                              void* d_out, int out_size, void* d_ws, size_t ws_size,
                              hipStream_t stream) {
  const float* x     = (const float*)d_in[0];
  const float* cproj = (const float*)d_in[1];
  const float* wq    = (const float*)d_in[2];
  const float* bq    = (const float*)d_in[3];
  const float* wkv   = (const float*)d_in[4];
  const float* bkv   = (const float*)d_in[5];
  const float* wo    = (const float*)d_in[6];
  const float* bo    = (const float*)d_in[7];
  float* out = (float*)d_out;

  unsigned short* xT    = (unsigned short*)d_ws;
  unsigned short* cpT   = xT + 8388608;
  unsigned short* qT    = cpT + 8388608;
  float*          Kf    = (float*)(qT + 8388608);
  unsigned short* Vb    = (unsigned short*)(Kf + 8388608);
  unsigned short* wqb   = Vb + 8388608;
  unsigned short* wkvb  = wqb + 65536;
  unsigned short* wob   = wkvb + 131072;
  unsigned short* ctxsT = wob + 65536;
  unsigned short* ctx2  = ctxsT + 524288;
  unsigned short* kb    = xT;            // alias: xT dead after qproj
  float*          ctxp  = (float*)cpT;   // alias: cpT dead after kvproj

  castw<<<256, 256, 0, stream>>>(wq, wkv, wo, wqb, wkvb, wob);
  transpose_cast<<<dim3(64, 4, 16), 256, 0, stream>>>(x, cproj, xT, cpT);
  qproj<<<dim3(64, 1, 8), 256, 0, stream>>>(wqb, xT, bq, qT);
  kvproj<<<dim3(64, 1, 8), 256, 0, stream>>>(wkvb, cpT, bkv, Kf, Vb);
  ksoftmax<<<2048, 256, 0, stream>>>(Kf, kb);
  ctx_part<<<dim3(4, 2, 64), 256, 0, stream>>>(kb, Vb, ctxp);
  ctx_reduce_t<<<dim3(4, 4, 8), 256, 0, stream>>>(ctxp, ctxsT);
  oproj<<<dim3(2, 2, 8), 256, 0, stream>>>(wob, ctxsT, ctx2);
  outgemm<<<dim3(64, 1, 8), 256, 0, stream>>>(ctx2, qT, bo, out);
}

// Round 7
// 199.300 us; speedup vs baseline: 1.0712x; 1.0712x over previous
//
#include <hip/hip_runtime.h>

#define B_ 8
#define C_ 256
#define N_ 4096
#define NSPLIT 8

typedef float f32x4 __attribute__((ext_vector_type(4)));
typedef __bf16 bf16x8 __attribute__((ext_vector_type(8)));
typedef unsigned short u16x8 __attribute__((ext_vector_type(8)));
typedef unsigned short u16x4 __attribute__((ext_vector_type(4)));

__device__ __forceinline__ unsigned short f2bf(float f) {
  unsigned u = __float_as_uint(f);
  u += 0x7fff + ((u >> 16) & 1);   // RNE; inputs finite
  return (unsigned short)(u >> 16);
}

__device__ __forceinline__ f32x4 mfma16(bf16x8 a, bf16x8 b, f32x4 c) {
  return __builtin_amdgcn_mfma_f32_16x16x32_bf16(a, b, c, 0, 0, 0);
}

typedef __attribute__((address_space(1))) const void* gvp;
typedef __attribute__((address_space(3))) void* lvp;
__device__ __forceinline__ void gld16(const void* g, void* l) {
  __builtin_amdgcn_global_load_lds((gvp)g, (lvp)l, 16, 0, 0);
}

// Swizzled LDS tile (bf16 sources): ROWS x 64 bf16, pitch 64 u16; chunk c of
// row r at slot c^(r&7). Staged with global_load_lds (16 B/lane, async).
template <int ROWS>
__device__ __forceinline__ void stage(unsigned short* lds, const unsigned short* g,
                                      int ld, int w, int lane) {
  const int r8 = lane >> 3;
  const int ce = ((lane & 7) ^ r8) << 3;
  const unsigned short* gp = g + (size_t)(w * (ROWS / 4) + r8) * ld + ce;
  unsigned short* lp = lds + w * (ROWS / 4) * 64;
#pragma unroll
  for (int i = 0; i < ROWS / 32; i++)
    gld16(gp + (size_t)(i * 8) * ld, lp + i * 512);
}

__device__ __forceinline__ bf16x8 frag(const unsigned short* lds, int row, int kc) {
  return *(const bf16x8*)(lds + row * 64 + ((kc ^ (row & 7)) << 3));
}

// Fused-transpose B tile (fp32 [k][n] source -> bf16 [n][k] LDS, pitch 68).
// Loads: 4 coalesced float4 per thread (4 k-rows x 4 n). Writes: 4 ds_write_b64
// (4-way, cheap). Frag reads: two conflict-free ds_read_b64.
__device__ __forceinline__ void loadB(float4* pbv, const float* src, int ld,
                                      int n0, int kt, int w, int lane) {
  const int nf = lane & 15, kg = lane >> 4;
  const float* sp = src + (size_t)(kt * 64 + w * 16 + kg * 4) * ld + n0 + 4 * nf;
#pragma unroll
  for (int i = 0; i < 4; i++) pbv[i] = *(const float4*)(sp + (size_t)i * ld);
}
__device__ __forceinline__ void writeB(unsigned short* Bs, const float4* pbv,
                                       int w, int lane) {
  const int nf = lane & 15, kg = lane >> 4;
  const int k0 = w * 16 + kg * 4;
#pragma unroll
  for (int j = 0; j < 4; j++) {
    u16x4 o = (u16x4){f2bf(((const float*)&pbv[0])[j]), f2bf(((const float*)&pbv[1])[j]),
                      f2bf(((const float*)&pbv[2])[j]), f2bf(((const float*)&pbv[3])[j])};
    *(u16x4*)&Bs[(4 * nf + j) * 68 + k0] = o;
  }
}
__device__ __forceinline__ bf16x8 fragB(const unsigned short* Bs, int n, int k8) {
  union { u16x4 q[2]; bf16x8 b; } u;
  const unsigned short* p = Bs + n * 68 + k8 * 8;
  u.q[0] = *(const u16x4*)p;
  u.q[1] = *(const u16x4*)(p + 4);
  return u.b;
}

// ---------------------------------------------------------------------------
// P1: cast weights fp32 -> bf16
__global__ __launch_bounds__(256) void castw(
    const float* __restrict__ wq, const float* __restrict__ wkv,
    const float* __restrict__ wo, unsigned short* __restrict__ wqb,
    unsigned short* __restrict__ wkvb, unsigned short* __restrict__ wob) {
  int i = (blockIdx.x * 256 + threadIdx.x) * 4;
  const float* src;
  unsigned short* dst;
  int off;
  if (i < 65536) { src = wq; dst = wqb; off = i; }
  else if (i < 196608) { src = wkv; dst = wkvb; off = i - 65536; }
  else { src = wo; dst = wob; off = i - 196608; }
  float4 v = *(const float4*)(src + off);
  *(u16x4*)(dst + off) = (u16x4){f2bf(v.x), f2bf(v.y), f2bf(v.z), f2bf(v.w)};
}

// ---------------------------------------------------------------------------
// G1: qT[b][n][m] = softmax_d((wq @ x + bq) * 0.25). M-tile 256 (full C) x
// N-tile 64, BK=64. B staged from x fp32 with fused transpose. Wave w = head w.
__global__ __launch_bounds__(256) void qproj(
    const unsigned short* __restrict__ wqb, const float* __restrict__ x,
    const float* __restrict__ bq, unsigned short* __restrict__ qT) {
  __shared__ __align__(16) unsigned short As[256 * 64];
  __shared__ __align__(16) unsigned short Bs[64 * 68];
  const int b = blockIdx.z, n0 = blockIdx.x * 64;
  const int tid = threadIdx.x, lane = tid & 63, w = tid >> 6;
  const int m0w = w * 64;
  const int colL = lane & 15, kq = lane >> 4, quad = lane >> 4;
  const float* xb = x + (size_t)b * C_ * N_;

  f32x4 acc[4][4];
#pragma unroll
  for (int i = 0; i < 4; i++)
#pragma unroll
    for (int j = 0; j < 4; j++) acc[i][j] = (f32x4){0.f, 0.f, 0.f, 0.f};

  float4 pbv[4];
  loadB(pbv, xb, N_, n0, 0, w, lane);

  for (int kt = 0; kt < 4; kt++) {
    writeB(Bs, pbv, w, lane);
    stage<256>(As, wqb + kt * 64, C_, w, lane);
    __syncthreads();
    if (kt < 3) loadB(pbv, xb, N_, n0, kt + 1, w, lane);
#pragma unroll
    for (int ks = 0; ks < 2; ks++) {
      bf16x8 af[4], bf[4];
#pragma unroll
      for (int mt = 0; mt < 4; mt++) af[mt] = frag(As, m0w + mt * 16 + colL, ks * 4 + kq);
#pragma unroll
      for (int nt = 0; nt < 4; nt++) bf[nt] = fragB(Bs, nt * 16 + colL, ks * 4 + kq);
#pragma unroll
      for (int mt = 0; mt < 4; mt++)
#pragma unroll
        for (int nt = 0; nt < 4; nt++) acc[mt][nt] = mfma16(af[mt], bf[nt], acc[mt][nt]);
    }
    __syncthreads();
  }

  // per-column softmax over this wave's head (64 channels)
#pragma unroll
  for (int nt = 0; nt < 4; nt++) {
    float v[16];
    float mx = -1e30f;
#pragma unroll
    for (int mt = 0; mt < 4; mt++)
#pragma unroll
      for (int r = 0; r < 4; r++) {
        int m = m0w + mt * 16 + quad * 4 + r;
        float val = (acc[mt][nt][r] + bq[m]) * 0.25f;
        v[mt * 4 + r] = val;
        mx = fmaxf(mx, val);
      }
    mx = fmaxf(mx, __shfl_xor(mx, 16));
    mx = fmaxf(mx, __shfl_xor(mx, 32));
    float s = 0.f;
#pragma unroll
    for (int j = 0; j < 16; j++) { v[j] = __expf(v[j] - mx); s += v[j]; }
    s += __shfl_xor(s, 16);
    s += __shfl_xor(s, 32);
    float inv = 1.0f / s;
    const int n = n0 + nt * 16 + colL;
    unsigned short* qb = qT + ((size_t)b * N_ + n) * C_ + m0w;
#pragma unroll
    for (int mt = 0; mt < 4; mt++) {
      u16x4 o = (u16x4){f2bf(v[mt * 4 + 0] * inv), f2bf(v[mt * 4 + 1] * inv),
                        f2bf(v[mt * 4 + 2] * inv), f2bf(v[mt * 4 + 3] * inv)};
      *(u16x4*)(qb + mt * 16 + quad * 4) = o;
    }
  }
}

// ---------------------------------------------------------------------------
// G2: KV = wkv @ cproj + bkv. M-tile 512 (full KVC) x N-tile 64, BK=64.
// B staged from cproj fp32 with fused transpose. K rows -> fp32, V -> bf16.
__global__ __launch_bounds__(256) void kvproj(
    const unsigned short* __restrict__ wkvb, const float* __restrict__ cp,
    const float* __restrict__ bkv, float* __restrict__ Kf,
    unsigned short* __restrict__ Vb) {
  __shared__ __align__(16) unsigned short As[512 * 64];
  __shared__ __align__(16) unsigned short Bs[64 * 68];
  const int b = blockIdx.z, n0 = blockIdx.x * 64;
  const int tid = threadIdx.x, lane = tid & 63, w = tid >> 6;
  const int m0w = w * 128;
  const int colL = lane & 15, kq = lane >> 4, quad = lane >> 4;
  const float* cpb = cp + (size_t)b * C_ * N_;

  f32x4 acc[8][4];
#pragma unroll
  for (int i = 0; i < 8; i++)
#pragma unroll
    for (int j = 0; j < 4; j++) acc[i][j] = (f32x4){0.f, 0.f, 0.f, 0.f};

  float4 pbv[4];
  loadB(pbv, cpb, N_, n0, 0, w, lane);

  for (int kt = 0; kt < 4; kt++) {
    writeB(Bs, pbv, w, lane);
    stage<512>(As, wkvb + kt * 64, C_, w, lane);
    __syncthreads();
    if (kt < 3) loadB(pbv, cpb, N_, n0, kt + 1, w, lane);
#pragma unroll
    for (int ks = 0; ks < 2; ks++) {
      bf16x8 bf[4];
#pragma unroll
      for (int nt = 0; nt < 4; nt++) bf[nt] = fragB(Bs, nt * 16 + colL, ks * 4 + kq);
#pragma unroll
      for (int mt = 0; mt < 8; mt++) {
        bf16x8 af = frag(As, m0w + mt * 16 + colL, ks * 4 + kq);
#pragma unroll
        for (int nt = 0; nt < 4; nt++) acc[mt][nt] = mfma16(af, bf[nt], acc[mt][nt]);
      }
    }
    __syncthreads();
  }

#pragma unroll
  for (int mt = 0; mt < 8; mt++)
#pragma unroll
    for (int r = 0; r < 4; r++) {
      int m = m0w + mt * 16 + quad * 4 + r;
      float bias = bkv[m];
      if (m < C_) {
        float* kr = Kf + ((size_t)b * C_ + m) * N_ + n0;
#pragma unroll
        for (int nt = 0; nt < 4; nt++) kr[nt * 16 + colL] = acc[mt][nt][r] + bias;
      } else {
        unsigned short* vr = Vb + ((size_t)b * C_ + m - C_) * N_ + n0;
#pragma unroll
        for (int nt = 0; nt < 4; nt++) vr[nt * 16 + colL] = f2bf(acc[mt][nt][r] + bias);
      }
    }
}

// ---------------------------------------------------------------------------
// G3: kb = softmax_N(Kf) bf16, one block per (b, c) row of 4096.
__global__ __launch_bounds__(256) void ksoftmax(const float* __restrict__ Kf,
                                                unsigned short* __restrict__ kb) {
  const int b = blockIdx.x >> 8, c = blockIdx.x & 255;
  const float* row = Kf + ((size_t)b * C_ + c) * N_;
  unsigned short* orow = kb + ((size_t)b * C_ + c) * N_;
  const int t = threadIdx.x, lane = t & 63, wv = t >> 6;
  __shared__ float red[8];

  float4 v[4];
  float mx = -1e30f;
#pragma unroll
  for (int i = 0; i < 4; i++) {
    v[i] = *(const float4*)&row[i * 1024 + t * 4];
    mx = fmaxf(fmaxf(fmaxf(mx, v[i].x), fmaxf(v[i].y, v[i].z)), v[i].w);
  }
#pragma unroll
  for (int o = 32; o > 0; o >>= 1) mx = fmaxf(mx, __shfl_down(mx, o));
  if (lane == 0) red[wv] = mx;
  __syncthreads();
  mx = fmaxf(fmaxf(red[0], red[1]), fmaxf(red[2], red[3]));

  float s = 0.f;
#pragma unroll
  for (int i = 0; i < 4; i++) {
    v[i].x = __expf(v[i].x - mx); v[i].y = __expf(v[i].y - mx);
    v[i].z = __expf(v[i].z - mx); v[i].w = __expf(v[i].w - mx);
    s += v[i].x + v[i].y + v[i].z + v[i].w;
  }
#pragma unroll
  for (int o = 32; o > 0; o >>= 1) s += __shfl_down(s, o);
  if (lane == 0) red[4 + wv] = s;
  __syncthreads();
  float inv = 1.0f / (red[4] + red[5] + red[6] + red[7]);
#pragma unroll
  for (int i = 0; i < 4; i++) {
    u16x4 o = (u16x4){f2bf(v[i].x * inv), f2bf(v[i].y * inv),
                      f2bf(v[i].z * inv), f2bf(v[i].w * inv)};
    *(u16x4*)&orow[i * 1024 + t * 4] = o;
  }
}

// ---------------------------------------------------------------------------
// G4: ctxp[s][b][c][d] = sum_{n in split s} kb[b][c][n] * Vb[b][d][n].
// NT GEMM 128x64, BK=64.
__global__ __launch_bounds__(256) void ctx_part(
    const unsigned short* __restrict__ kb, const unsigned short* __restrict__ Vb,
    float* __restrict__ ctxp) {
  __shared__ __align__(16) unsigned short As[128 * 64];
  __shared__ __align__(16) unsigned short Bs[64 * 64];
  const int z = blockIdx.z, b = z >> 3, s = z & 7;
  const int m0 = blockIdx.y * 128, n0 = blockIdx.x * 64;
  const int tid = threadIdx.x, lane = tid & 63, w = tid >> 6;
  const int m0w = (w & 1) * 64, n0w = (w >> 1) * 32;
  const int colL = lane & 15, kq = lane >> 4, quad = lane >> 4;
  const unsigned short* Ag = kb + ((size_t)b * C_ + m0) * N_;
  const unsigned short* Bg = Vb + ((size_t)b * C_ + n0) * N_;
  const int kbeg = s * (N_ / NSPLIT);

  f32x4 acc[4][2];
#pragma unroll
  for (int i = 0; i < 4; i++)
#pragma unroll
    for (int j = 0; j < 2; j++) acc[i][j] = (f32x4){0.f, 0.f, 0.f, 0.f};

  for (int kt = 0; kt < (N_ / NSPLIT) / 64; kt++) {
    stage<128>(As, Ag + kbeg + kt * 64, N_, w, lane);
    stage<64>(Bs, Bg + kbeg + kt * 64, N_, w, lane);
    __syncthreads();
#pragma unroll
    for (int ks = 0; ks < 2; ks++) {
      bf16x8 af[4], bf[2];
#pragma unroll
      for (int mt = 0; mt < 4; mt++) af[mt] = frag(As, m0w + mt * 16 + colL, ks * 4 + kq);
#pragma unroll
      for (int nt = 0; nt < 2; nt++) bf[nt] = frag(Bs, n0w + nt * 16 + colL, ks * 4 + kq);
#pragma unroll
      for (int mt = 0; mt < 4; mt++)
#pragma unroll
        for (int nt = 0; nt < 2; nt++) acc[mt][nt] = mfma16(af[mt], bf[nt], acc[mt][nt]);
    }
    __syncthreads();
  }

  float* outp = ctxp + ((size_t)s * B_ + b) * C_ * C_;
#pragma unroll
  for (int mt = 0; mt < 4; mt++)
#pragma unroll
    for (int nt = 0; nt < 2; nt++)
#pragma unroll
      for (int r = 0; r < 4; r++) {
        int m = m0 + m0w + mt * 16 + quad * 4 + r;
        int n = n0 + n0w + nt * 16 + colL;
        outp[(size_t)m * C_ + n] = acc[mt][nt][r];
      }
}

// ---------------------------------------------------------------------------
// R: ctxsT[b][d][c] bf16 = transpose(sum over 8 split partials).
__global__ __launch_bounds__(256) void ctx_reduce_t(const float* __restrict__ ctxp,
                                                    unsigned short* __restrict__ ctxsT) {
  __shared__ unsigned short t[64][72];
  const int b = blockIdx.z, c0 = blockIdx.y * 64, d0 = blockIdx.x * 64;
  const int tid = threadIdx.x;
  const int cl = tid >> 2, dg = (tid & 3) * 16;
  const float* base = ctxp + ((size_t)b * C_ + c0 + cl) * C_ + d0 + dg;
  float acc[16];
#pragma unroll
  for (int j = 0; j < 16; j++) acc[j] = 0.f;
  for (int s = 0; s < NSPLIT; s++) {
    const float* p = base + (size_t)s * B_ * C_ * C_;
#pragma unroll
    for (int j = 0; j < 16; j += 4) {
      float4 v = *(const float4*)(p + j);
      acc[j] += v.x; acc[j + 1] += v.y; acc[j + 2] += v.z; acc[j + 3] += v.w;
    }
  }
#pragma unroll
  for (int j = 0; j < 16; j++) t[dg + j][cl] = f2bf(acc[j]);
  __syncthreads();
  const int dr = tid >> 2, cg = (tid & 3) * 16;
  unsigned short* dp = ctxsT + ((size_t)b * C_ + d0 + dr) * C_ + c0 + cg;
  *(u16x8*)dp = *(const u16x8*)&t[dr][cg];
  *(u16x8*)(dp + 8) = *(const u16x8*)&t[dr][cg + 8];
}

// ---------------------------------------------------------------------------
// G5: ctx2[b][o][d] = wo @ ctx. NT GEMM 128x128, BK=64.
__global__ __launch_bounds__(256) void oproj(
    const unsigned short* __restrict__ wob, const unsigned short* __restrict__ ctxsT,
    unsigned short* __restrict__ ctx2) {
  __shared__ __align__(16) unsigned short As[128 * 64];
  __shared__ __align__(16) unsigned short Bs[128 * 64];
  const int b = blockIdx.z, m0 = blockIdx.y * 128, n0 = blockIdx.x * 128;
  const int tid = threadIdx.x, lane = tid & 63, w = tid >> 6;
  const int m0w = (w >> 1) * 64, n0w = (w & 1) * 64;
  const int colL = lane & 15, kq = lane >> 4, quad = lane >> 4;
  const unsigned short* Ag = wob + (size_t)m0 * C_;
  const unsigned short* Bg = ctxsT + ((size_t)b * C_ + n0) * C_;

  f32x4 acc[4][4];
#pragma unroll
  for (int i = 0; i < 4; i++)
#pragma unroll
    for (int j = 0; j < 4; j++) acc[i][j] = (f32x4){0.f, 0.f, 0.f, 0.f};

  for (int kt = 0; kt < 4; kt++) {
    stage<128>(As, Ag + kt * 64, C_, w, lane);
    stage<128>(Bs, Bg + kt * 64, C_, w, lane);
    __syncthreads();
#pragma unroll
    for (int ks = 0; ks < 2; ks++) {
      bf16x8 af[4], bf[4];
#pragma unroll
      for (int mt = 0; mt < 4; mt++) af[mt] = frag(As, m0w + mt * 16 + colL, ks * 4 + kq);
#pragma unroll
      for (int nt = 0; nt < 4; nt++) bf[nt] = frag(Bs, n0w + nt * 16 + colL, ks * 4 + kq);
#pragma unroll
      for (int mt = 0; mt < 4; mt++)
#pragma unroll
        for (int nt = 0; nt < 4; nt++) acc[mt][nt] = mfma16(af[mt], bf[nt], acc[mt][nt]);
    }
    __syncthreads();
  }

  unsigned short* ob = ctx2 + (size_t)b * C_ * C_;
#pragma unroll
  for (int mt = 0; mt < 4; mt++)
#pragma unroll
    for (int nt = 0; nt < 4; nt++)
#pragma unroll
      for (int r = 0; r < 4; r++) {
        int m = m0 + m0w + mt * 16 + quad * 4 + r;
        int n = n0 + n0w + nt * 16 + colL;
        ob[(size_t)m * C_ + n] = f2bf(acc[mt][nt][r]);
      }
}

// ---------------------------------------------------------------------------
// G6: out[b][m][n] = sum_d ctx2[b][m][d] * qT[b][n][d] + bo[m]. NT GEMM,
// M-tile 256 x N-tile 64, BK=64 (qT read once).
__global__ __launch_bounds__(256) void outgemm(
    const unsigned short* __restrict__ ctx2, const unsigned short* __restrict__ qT,
    const float* __restrict__ bo, float* __restrict__ out) {
  __shared__ __align__(16) unsigned short As[256 * 64];
  __shared__ __align__(16) unsigned short Bs[64 * 64];
  const int b = blockIdx.z, n0 = blockIdx.x * 64;
  const int tid = threadIdx.x, lane = tid & 63, w = tid >> 6;
  const int m0w = w * 64;
  const int colL = lane & 15, kq = lane >> 4, quad = lane >> 4;
  const unsigned short* Ag = ctx2 + (size_t)b * C_ * C_;
  const unsigned short* Bg = qT + ((size_t)b * N_ + n0) * C_;

  f32x4 acc[4][4];
#pragma unroll
  for (int i = 0; i < 4; i++)
#pragma unroll
    for (int j = 0; j < 4; j++) acc[i][j] = (f32x4){0.f, 0.f, 0.f, 0.f};

  for (int kt = 0; kt < 4; kt++) {
    stage<256>(As, Ag + kt * 64, C_, w, lane);
    stage<64>(Bs, Bg + kt * 64, C_, w, lane);
    __syncthreads();
#pragma unroll
    for (int ks = 0; ks < 2; ks++) {
      bf16x8 af[4], bf[4];
#pragma unroll
      for (int mt = 0; mt < 4; mt++) af[mt] = frag(As, m0w + mt * 16 + colL, ks * 4 + kq);
#pragma unroll
      for (int nt = 0; nt < 4; nt++) bf[nt] = frag(Bs, nt * 16 + colL, ks * 4 + kq);
#pragma unroll
      for (int mt = 0; mt < 4; mt++)
#pragma unroll
        for (int nt = 0; nt < 4; nt++) acc[mt][nt] = mfma16(af[mt], bf[nt], acc[mt][nt]);
    }
    __syncthreads();
  }

  float* ob = out + (size_t)b * C_ * N_;
#pragma unroll
  for (int mt = 0; mt < 4; mt++)
#pragma unroll
    for (int r = 0; r < 4; r++) {
      int m = m0w + mt * 16 + quad * 4 + r;
      float bias = bo[m];
#pragma unroll
      for (int nt = 0; nt < 4; nt++) {
        int n = n0 + nt * 16 + colL;
        ob[(size_t)m * N_ + n] = acc[mt][nt][r] + bias;
      }
    }
}

// ---------------------------------------------------------------------------
extern "C" void kernel_launch(void* const* d_in, const int* in_sizes, int n_in,
                              void* d_out, int out_size, void* d_ws, size_t ws_size,
                              hipStream_t stream) {
  const float* x     = (const float*)d_in[0];
  const float* cproj = (const float*)d_in[1];
  const float* wq    = (const float*)d_in[2];
  const float* bq    = (const float*)d_in[3];
  const float* wkv   = (const float*)d_in[4];
  const float* bkv   = (const float*)d_in[5];
  const float* wo    = (const float*)d_in[6];
  const float* bo    = (const float*)d_in[7];
  float* out = (float*)d_out;

  // workspace (~104 MB), no aliasing needed (transpose buffers eliminated)
  unsigned short* qT    = (unsigned short*)d_ws;            // 8.39M u16
  float*          Kf    = (float*)(qT + 8388608);           // 8.39M f32
  unsigned short* Vb    = (unsigned short*)(Kf + 8388608);  // 8.39M u16
  unsigned short* kb    = Vb + 8388608;                     // 8.39M u16
  float*          ctxp  = (float*)(kb + 8388608);           // 4.19M f32
  unsigned short* wqb   = (unsigned short*)(ctxp + 4194304);
  unsigned short* wkvb  = wqb + 65536;
  unsigned short* wob   = wkvb + 131072;
  unsigned short* ctxsT = wob + 65536;
  unsigned short* ctx2  = ctxsT + 524288;

  castw<<<256, 256, 0, stream>>>(wq, wkv, wo, wqb, wkvb, wob);
  qproj<<<dim3(64, 1, 8), 256, 0, stream>>>(wqb, x, bq, qT);
  kvproj<<<dim3(64, 1, 8), 256, 0, stream>>>(wkvb, cproj, bkv, Kf, Vb);
  ksoftmax<<<2048, 256, 0, stream>>>(Kf, kb);
  ctx_part<<<dim3(4, 2, 64), 256, 0, stream>>>(kb, Vb, ctxp);
  ctx_reduce_t<<<dim3(4, 4, 8), 256, 0, stream>>>(ctxp, ctxsT);
  oproj<<<dim3(2, 2, 8), 256, 0, stream>>>(wob, ctxsT, ctx2);
  outgemm<<<dim3(64, 1, 8), 256, 0, stream>>>(ctx2, qT, bo, out);
}